// Round 16
// baseline (268.921 us; speedup 1.0000x reference)
//
#include <hip/hip_runtime.h>
#include <hip/hip_bf16.h>
#include <math.h>

#define BB   8
#define CCH  192
#define OCN  576
#define HWD  128
#define HWN  16384
#define NH   4
#define CHD  48
#define C51  51
#define GSZ  (C51*48)   // 2448 dense gram tile

typedef __hip_bfloat16 bf16;
typedef __attribute__((ext_vector_type(8))) short short8;
typedef __attribute__((ext_vector_type(4))) float f32x4;

__device__ __forceinline__ float bfbits2f(unsigned int u16) {
  union { unsigned int i; float f; } v; v.i = u16 << 16; return v.f;
}
__device__ __forceinline__ unsigned short f2bfbits(float f) {
  __hip_bfloat16 h = __float2bfloat16(f);
  return *(unsigned short*)&h;
}
__device__ __forceinline__ void stage16(const void* g, void* l) {
  __builtin_amdgcn_global_load_lds(
      (const __attribute__((address_space(1))) void*)g,
      (__attribute__((address_space(3))) void*)l, 16, 0, 0);
}

// ------- K0: svp 1x1 conv (3 -> 12) + per-block ssq partials (no atomics) ---
__global__ __launch_bounds__(256) void k_svp(
    const float* __restrict__ svp_fea, const float* __restrict__ svp_w,
    float* __restrict__ svp_q, float* __restrict__ ssq_svp_p)
{
  __shared__ float lsw[4][12];
  const int b = blockIdx.y;
  const int t = threadIdx.x;
  const int n = blockIdx.x * 256 + t;
  const int wave = t >> 6;
  const float* fb = svp_fea + (size_t)b * 3 * HWN;
  const float f0 = fb[n], f1 = fb[HWN + n], f2 = fb[2 * HWN + n];
  float* ob = svp_q + (size_t)b * 12 * HWN + n;
  #pragma unroll
  for (int r = 0; r < 12; ++r) {
    float o = svp_w[r*3]*f0 + svp_w[r*3+1]*f1 + svp_w[r*3+2]*f2;
    ob[(size_t)r * HWN] = o;
    float v = o * o;
    #pragma unroll
    for (int off = 32; off >= 1; off >>= 1) v += __shfl_down(v, off, 64);
    if ((t & 63) == 0) lsw[wave][r] = v;
  }
  __syncthreads();
  if (t < 12) {
    float s = lsw[0][t] + lsw[1][t] + lsw[2][t] + lsw[3][t];
    ssq_svp_p[((size_t)b * 12 + t) * 64 + blockIdx.x] = s;
  }
}

// ---------------- K0b: cast qkv_w (576x192 f32) -> bf16 ---------------------
__global__ __launch_bounds__(256) void k_castw(
    const float* __restrict__ w, unsigned short* __restrict__ wb)
{
  const int i = (blockIdx.x * 256 + threadIdx.x) * 4;
  float4 v = *(const float4*)(w + i);
  union { uint2 u; unsigned short s[4]; } pk;
  pk.s[0] = f2bfbits(v.x); pk.s[1] = f2bfbits(v.y);
  pk.s[2] = f2bfbits(v.z); pk.s[3] = f2bfbits(v.w);
  *(uint2*)(wb + i) = pk.u;
}

// ---------- K1: qkv1 = W(bf16) @ x(f32->bf16), MFMA 16x16x32 ----------------
// BN=128, swapped operands, T-epilogue (256B stores), two-phase X staging.
__global__ __launch_bounds__(256) void k_gemm(
    const float* __restrict__ x, const unsigned short* __restrict__ wb,
    unsigned short* __restrict__ qkv1)
{
  __shared__ unsigned short Xs[64 * CCH];     // 24 KB; first 8 KB reused as T
  __shared__ unsigned short Wd[2][32 * CCH];  // 2 x 12 KB
  const int b = blockIdx.y;
  const int n0 = blockIdx.x * 128;
  const int t = threadIdx.x;
  const int lane = t & 63, wave = t >> 6;
  const int wm = wave >> 1, wn = wave & 1;
  const int lq = lane >> 4, lr = lane & 15;

  // issue W chunk 0 early (latency hides under X staging)
  #pragma unroll
  for (int i = 0; i < 3; ++i) {
    int chunk = wave * 3 + i;
    int d = chunk * 64 + lane;
    int row = d / 24, kg = d % 24;
    int skg = (kg & ~7) | ((kg & 7) ^ (row & 7));
    stage16(wb + (size_t)row * CCH + skg * 8, &Wd[0][0] + chunk * 512);
  }

  const float* xb = x + (size_t)b * CCH * HWN + n0;
  short8 bfr[4][6];
  #pragma unroll 1
  for (int ph = 0; ph < 2; ++ph) {
    #pragma unroll
    for (int rr = 0; rr < 6; ++rr) {
      int idx = rr * 256 + t;
      int cp = idx >> 4, nq = idx & 15;
      int c0 = cp * 2;
      const float* xsrc = xb + (size_t)c0 * HWN + ph * 64 + nq * 4;
      float4 v0 = *(const float4*)xsrc;
      float4 v1 = *(const float4*)(xsrc + HWN);
      int g = c0 >> 3, co = c0 & 7;
      float a0[4] = {v0.x, v0.y, v0.z, v0.w};
      float a1[4] = {v1.x, v1.y, v1.z, v1.w};
      #pragma unroll
      for (int j = 0; j < 4; ++j) {
        int n = nq * 4 + j;   // local row 0..63
        int gs = (g & ~7) | ((g & 7) ^ (n & 7) ^ ((n >> 3) & 7));
        unsigned int pk = (unsigned int)f2bfbits(a0[j])
                        | ((unsigned int)f2bfbits(a1[j]) << 16);
        *(unsigned int*)&Xs[n * CCH + gs * 8 + co] = pk;
      }
    }
    __syncthreads();
    if (wn == ph) {
      #pragma unroll
      for (int nf = 0; nf < 4; ++nf) {
        int r = nf * 16 + lr;   // local row
        #pragma unroll
        for (int ks = 0; ks < 6; ++ks) {
          int gk = ks * 4 + lq;
          int sg = (gk & ~7) | ((gk & 7) ^ (r & 7) ^ ((r >> 3) & 7));
          bfr[nf][ks] = *(const short8*)&Xs[r * CCH + sg * 8];
        }
      }
    }
    __syncthreads();
  }

  unsigned short* T = &Xs[0];  // 32 x 128 bf16 transpose tile (8 KB)

  for (int mc = 0; mc < 18; ++mc) {
    if (mc + 1 < 18) {
      const unsigned short* wsrc = wb + (size_t)(mc + 1) * 32 * CCH;
      unsigned short* nb = &Wd[(mc + 1) & 1][0];
      #pragma unroll
      for (int i = 0; i < 3; ++i) {
        int chunk = wave * 3 + i;
        int d = chunk * 64 + lane;
        int row = d / 24, kg = d % 24;
        int skg = (kg & ~7) | ((kg & 7) ^ (row & 7));
        stage16(wsrc + (size_t)row * CCH + skg * 8, nb + chunk * 512);
      }
      asm volatile("s_waitcnt vmcnt(3)" ::: "memory");
    } else {
      asm volatile("s_waitcnt vmcnt(0)" ::: "memory");
    }
    __builtin_amdgcn_s_barrier();
    asm volatile("" ::: "memory");

    const unsigned short* wbuf = &Wd[mc & 1][0];
    f32x4 acc[4];
    #pragma unroll
    for (int nf = 0; nf < 4; ++nf) acc[nf] = (f32x4)0.f;

    #pragma unroll
    for (int ks = 0; ks < 6; ++ks) {
      const int gk = ks * 4 + lq;
      int rW = wm * 16 + lr;
      int sg = (gk & ~7) | ((gk & 7) ^ (rW & 7));
      short8 w8 = *(const short8*)&wbuf[rW * CCH + sg * 8];
      #pragma unroll
      for (int nf = 0; nf < 4; ++nf)
        acc[nf] = __builtin_amdgcn_mfma_f32_16x16x32_bf16(
            bfr[nf][ks], w8, acc[nf], 0, 0, 0);
    }

    {
      int m = wm * 16 + lr;  // local row 0..31
      #pragma unroll
      for (int nf = 0; nf < 4; ++nf) {
        union { unsigned long long u; unsigned short s[4]; } pk;
        #pragma unroll
        for (int r = 0; r < 4; ++r) pk.s[r] = f2bfbits(acc[nf][r]);
        int off = (m * 256 + wn * 128 + nf * 32 + lq * 8) ^ ((m & 15) << 4);
        *(unsigned long long*)((char*)T + off) = pk.u;
      }
    }
    asm volatile("s_waitcnt lgkmcnt(0)" ::: "memory");
    __builtin_amdgcn_s_barrier();
    asm volatile("" ::: "memory");
    #pragma unroll
    for (int i = 0; i < 2; ++i) {
      int p = t + 256 * i;
      int row = p >> 4, seg = p & 15;
      int off = (row * 256 + seg * 16) ^ ((row & 15) << 4);
      uint4 v = *(const uint4*)((const char*)T + off);
      *(uint4*)(qkv1 + ((size_t)b * OCN + mc * 32 + row) * HWN + n0 + seg * 8) = v;
    }
    asm volatile("" ::: "memory");
    __builtin_amdgcn_s_barrier();
  }
}

// ---------- K1b: depthwise 3x3 conv, rolling 3-row window, 8 rows/thread ----
// block per (channel, batch); thread = 8 rows x 8 cols; load ratio 1.25.
__global__ __launch_bounds__(256) void k_dw(
    const unsigned short* __restrict__ qkv1, const float* __restrict__ dw_w,
    unsigned short* __restrict__ qkv, float* __restrict__ ssq_qk)
{
  __shared__ float lsw[4];
  const int b = blockIdx.y, c = blockIdx.x;
  const int t = threadIdx.x;
  const int cg = t & 15, rg = t >> 4;
  const int y0 = rg * 8;
  const unsigned short* src = qkv1 + ((size_t)b * OCN + c) * HWN;
  unsigned short* dst = qkv + ((size_t)b * OCN + c) * HWN;
  float w[9];
  #pragma unroll
  for (int i = 0; i < 9; ++i) w[i] = dw_w[c * 9 + i];

  auto load_row = [&](int gy, float* r) {
    uint4 B = make_uint4(0u, 0u, 0u, 0u);
    unsigned int Al = 0, Cv = 0;
    if ((unsigned)gy < 128u) {
      const unsigned short* rp = src + (size_t)gy * HWD;
      B = *(const uint4*)(rp + cg * 8);
      if (cg > 0)  Al = *(const unsigned int*)(rp + cg * 8 - 2);
      if (cg < 15) Cv = (unsigned int)rp[cg * 8 + 8];
    }
    r[0] = bfbits2f(Al >> 16);
    unsigned int ub[4] = {B.x, B.y, B.z, B.w};
    #pragma unroll
    for (int q = 0; q < 4; ++q) {
      r[1 + 2*q] = bfbits2f(ub[q] & 0xffffu);
      r[2 + 2*q] = bfbits2f(ub[q] >> 16);
    }
    r[9] = bfbits2f(Cv);
  };

  float rows[3][10];
  load_row(y0 - 1, rows[0]);
  load_row(y0,     rows[1]);
  float ssq = 0.f;
  #pragma unroll
  for (int e = 0; e < 8; ++e) {
    load_row(y0 + e + 1, rows[(e + 2) % 3]);
    const float* ra = rows[e % 3];
    const float* rb = rows[(e + 1) % 3];
    const float* rc = rows[(e + 2) % 3];
    float acc[8];
    #pragma unroll
    for (int i = 0; i < 8; ++i) acc[i] = 0.f;
    #pragma unroll
    for (int i = 0; i < 8; ++i)
      acc[i] += w[0]*ra[i] + w[1]*ra[i+1] + w[2]*ra[i+2];
    #pragma unroll
    for (int i = 0; i < 8; ++i)
      acc[i] += w[3]*rb[i] + w[4]*rb[i+1] + w[5]*rb[i+2];
    #pragma unroll
    for (int i = 0; i < 8; ++i)
      acc[i] += w[6]*rc[i] + w[7]*rc[i+1] + w[8]*rc[i+2];
    union { uint4 u; unsigned short s[8]; } pk;
    #pragma unroll
    for (int i = 0; i < 8; ++i) pk.s[i] = f2bfbits(acc[i]);
    *(uint4*)(dst + (size_t)(y0 + e) * HWD + cg * 8) = pk.u;
    if (c < 384) {
      #pragma unroll
      for (int i = 0; i < 8; ++i) {
        float rv = bfbits2f(pk.s[i]);
        ssq += rv * rv;
      }
    }
  }
  if (c < 384) {
    #pragma unroll
    for (int off = 32; off >= 1; off >>= 1) ssq += __shfl_down(ssq, off, 64);
    if ((t & 63) == 0) lsw[t >> 6] = ssq;
  }
  __syncthreads();
  if (c < 384 && t == 0)
    ssq_qk[(size_t)b * 384 + c] = lsw[0] + lsw[1] + lsw[2] + lsw[3];
}

// ---------- K3: Gram partials via MFMA, direct global loads -----------------
__global__ __launch_bounds__(256) void k_gram(
    const unsigned short* __restrict__ qkv, const float* __restrict__ svp_q,
    float* __restrict__ Gp)
{
  __shared__ float Gs[C51 * 50];  // row stride 50: 2-way banks max
  const int chunk = blockIdx.x, h = blockIdx.y, b = blockIdx.z;
  const int t = threadIdx.x;
  const int lane = t & 63, wave = t >> 6;
  const int lq = lane >> 4, lr = lane & 15;
  const unsigned short* qb = qkv + ((size_t)b*OCN + h*CHD)*HWN;
  const unsigned short* kb = qkv + ((size_t)b*OCN + 192 + h*CHD)*HWN;
  const float* sb = svp_q + ((size_t)b*12 + h*3)*HWN;

  for (int idx = t; idx < C51*50; idx += 256) Gs[idx] = 0.f;

  f32x4 acc[3][3], sacc[3];
  #pragma unroll
  for (int mf = 0; mf < 3; ++mf)
    #pragma unroll
    for (int nf = 0; nf < 3; ++nf) acc[mf][nf] = (f32x4)0.f;
  #pragma unroll
  for (int nf = 0; nf < 3; ++nf) sacc[nf] = (f32x4)0.f;

  const int nbase = chunk * 1024 + wave * 256;
  #pragma unroll 4
  for (int ks = 0; ks < 8; ++ks) {
    const int n = nbase + ks * 32 + lq * 8;
    short8 a[3], bb[3];
    #pragma unroll
    for (int mf = 0; mf < 3; ++mf)
      a[mf] = *(const short8*)&qb[(size_t)(mf*16 + lr)*HWN + n];
    #pragma unroll
    for (int nf = 0; nf < 3; ++nf)
      bb[nf] = *(const short8*)&kb[(size_t)(nf*16 + lr)*HWN + n];
    union { short8 s8; unsigned short us[8]; } sv;
    #pragma unroll
    for (int i = 0; i < 8; ++i) sv.us[i] = 0;
    if (lr < 3) {
      const float* sp = sb + (size_t)lr*HWN + n;
      float4 v0 = *(const float4*)sp, v1 = *(const float4*)(sp + 4);
      sv.us[0] = f2bfbits(v0.x); sv.us[1] = f2bfbits(v0.y);
      sv.us[2] = f2bfbits(v0.z); sv.us[3] = f2bfbits(v0.w);
      sv.us[4] = f2bfbits(v1.x); sv.us[5] = f2bfbits(v1.y);
      sv.us[6] = f2bfbits(v1.z); sv.us[7] = f2bfbits(v1.w);
    }
    #pragma unroll
    for (int mf = 0; mf < 3; ++mf)
      #pragma unroll
      for (int nf = 0; nf < 3; ++nf)
        acc[mf][nf] = __builtin_amdgcn_mfma_f32_16x16x32_bf16(
            a[mf], bb[nf], acc[mf][nf], 0, 0, 0);
    #pragma unroll
    for (int nf = 0; nf < 3; ++nf)
      sacc[nf] = __builtin_amdgcn_mfma_f32_16x16x32_bf16(
          sv.s8, bb[nf], sacc[nf], 0, 0, 0);
  }

  __syncthreads();
  for (int w = 0; w < 4; ++w) {
    if (wave == w) {
      #pragma unroll
      for (int mf = 0; mf < 3; ++mf)
        #pragma unroll
        for (int nf = 0; nf < 3; ++nf)
          #pragma unroll
          for (int r = 0; r < 4; ++r)
            Gs[(mf*16 + lq*4 + r)*50 + nf*16 + lr] += acc[mf][nf][r];
      if (lq == 0) {
        #pragma unroll
        for (int nf = 0; nf < 3; ++nf)
          #pragma unroll
          for (int r = 0; r < 3; ++r)
            Gs[(48 + r)*50 + nf*16 + lr] += sacc[nf][r];
      }
    }
    __syncthreads();
  }
  float* Gout = Gp + ((size_t)((b*NH + h) * 16 + chunk)) * GSZ;
  for (int idx = t; idx < GSZ; idx += 256) {
    int row = idx / 48, col = idx - row * 48;
    Gout[idx] = Gs[row*50 + col];
  }
}

// ---- K4: reduce Gp + ssq; softmax; fold with proj_w -> W2 (bf16) -----------
__global__ __launch_bounds__(256) void k_attn_fold(
    const float* __restrict__ Gp, const float* __restrict__ ssq_qk,
    const float* __restrict__ ssq_svp_p, const float* __restrict__ temperature,
    const float* __restrict__ proj_w, unsigned short* __restrict__ W2bf)
{
  __shared__ float A[GSZ];
  __shared__ float qinv[C51];
  __shared__ float kinv[48];
  const int h = blockIdx.x, b = blockIdx.y;
  const int t = threadIdx.x;
  const float* Gb = Gp + ((size_t)(b*NH + h) * 16) * GSZ;
  if (t < 48)
    kinv[t] = 1.f / fmaxf(sqrtf(ssq_qk[(size_t)b*384 + 192 + h*48 + t]), 1e-12f);
  if (t >= 64 && t < 64 + C51) {
    int c = t - 64;
    float ss;
    if (c < 48) {
      ss = ssq_qk[(size_t)b*384 + h*48 + c];
    } else {
      const float* p = ssq_svp_p + ((size_t)b * 12 + h*3 + (c - 48)) * 64;
      float s0 = 0.f, s1 = 0.f, s2 = 0.f, s3 = 0.f;
      #pragma unroll
      for (int i = 0; i < 16; ++i) {
        float4 v = *(const float4*)(p + i * 4);
        s0 += v.x; s1 += v.y; s2 += v.z; s3 += v.w;
      }
      ss = (s0 + s1) + (s2 + s3);
    }
    qinv[c] = 1.f / fmaxf(sqrtf(ss), 1e-12f);
  }
  for (int idx = t; idx < GSZ; idx += 256) {
    float s = 0.f;
    #pragma unroll
    for (int c = 0; c < 16; ++c) s += Gb[(size_t)c * GSZ + idx];
    A[idx] = s;
  }
  __syncthreads();
  const float temp = temperature[h];
  if (t < C51) {
    float row[48];
    float m = -1e30f;
    const float qi = qinv[t] * temp;
    #pragma unroll
    for (int d = 0; d < 48; ++d) {
      float l = A[t*48 + d] * qi * kinv[d];
      row[d] = l; m = fmaxf(m, l);
    }
    float s = 0.f;
    #pragma unroll
    for (int d = 0; d < 48; ++d) { row[d] = expf(row[d] - m); s += row[d]; }
    const float inv = 1.f / s;
    #pragma unroll
    for (int d = 0; d < 48; ++d) A[t*48 + d] = row[d] * inv;
  }
  __syncthreads();
  for (int idx = t; idx < 192*48; idx += 256) {
    int o = idx / 48, d = idx - o*48;
    const float* pw = proj_w + o*204 + C51*h;
    float s = 0.f;
    #pragma unroll
    for (int c = 0; c < C51; ++c) s += pw[c] * A[c*48 + d];
    W2bf[((size_t)b*CCH + o)*CCH + h*48 + d] = f2bfbits(s);
  }
}

// ---------- K5: out[b] = W2b(bf16) @ v(bf16), T-epilogue fp32 stores --------
__global__ __launch_bounds__(256) void k_out(
    const unsigned short* __restrict__ qkv, const unsigned short* __restrict__ w2b,
    float* __restrict__ out)
{
  __shared__ unsigned short Vs[64 * CCH];     // 24 KB; first 8 KB reused as T
  __shared__ unsigned short Wd[2][32 * CCH];  // 2 x 12 KB
  const int b = blockIdx.y;
  const int n0 = blockIdx.x * 64;
  const int t = threadIdx.x;
  const int lane = t & 63, wave = t >> 6;
  const int wm = wave >> 1, wn = wave & 1;
  const int lq = lane >> 4, lr = lane & 15;

  const unsigned short* w2base = w2b + (size_t)b * CCH * CCH;
  #pragma unroll
  for (int i = 0; i < 3; ++i) {
    int chunk = wave * 3 + i;
    int d = chunk * 64 + lane;
    int row = d / 24, kg = d % 24;
    int skg = (kg & ~7) | ((kg & 7) ^ (row & 7));
    stage16(w2base + (size_t)row * CCH + skg * 8, &Wd[0][0] + chunk * 512);
  }

  const unsigned short* vb = qkv + ((size_t)b * OCN + 384) * HWN + n0;
  #pragma unroll
  for (int rr = 0; rr < 3; ++rr) {
    int idx = rr * 256 + t;
    int cp = idx >> 3, nq = idx & 7;
    int c0 = cp * 2;
    uint4 v0 = *(const uint4*)(vb + (size_t)c0 * HWN + nq * 8);
    uint4 v1 = *(const uint4*)(vb + (size_t)(c0 + 1) * HWN + nq * 8);
    union { uint4 u; unsigned short s[8]; } p0, p1;
    p0.u = v0; p1.u = v1;
    int g = c0 >> 3, co = c0 & 7;
    #pragma unroll
    for (int j = 0; j < 8; ++j) {
      int n = nq * 8 + j;
      int gs = (g & ~7) | ((g & 7) ^ (n & 7) ^ ((n >> 3) & 7));
      unsigned int pk = (unsigned int)p0.s[j] | ((unsigned int)p1.s[j] << 16);
      *(unsigned int*)&Vs[n * CCH + gs * 8 + co] = pk;
    }
  }
  __syncthreads();

  short8 bfr[2][6];
  #pragma unroll
  for (int nf = 0; nf < 2; ++nf) {
    int r = wn * 32 + nf * 16 + lr;
    #pragma unroll
    for (int ks = 0; ks < 6; ++ks) {
      int gk = ks * 4 + lq;
      int sg = (gk & ~7) | ((gk & 7) ^ (r & 7) ^ ((r >> 3) & 7));
      bfr[nf][ks] = *(const short8*)&Vs[r * CCH + sg * 8];
    }
  }
  __syncthreads();   // all waves done reading Vs before T (=Vs) is written

  char* T = (char*)&Vs[0];  // 32 m x 64 n fp32 transpose tile (8 KB)

  for (int mc = 0; mc < 6; ++mc) {
    if (mc + 1 < 6) {
      const unsigned short* wsrc = w2base + (size_t)(mc + 1) * 32 * CCH;
      unsigned short* nb = &Wd[(mc + 1) & 1][0];
      #pragma unroll
      for (int i = 0; i < 3; ++i) {
        int chunk = wave * 3 + i;
        int d = chunk * 64 + lane;
        int row = d / 24, kg = d % 24;
        int skg = (kg & ~7) | ((kg & 7) ^ (row & 7));
        stage16(wsrc + (size_t)row * CCH + skg * 8, nb + chunk * 512);
      }
      asm volatile("s_waitcnt vmcnt(3)" ::: "memory");
    } else {
      asm volatile("s_waitcnt vmcnt(0)" ::: "memory");
    }
    __builtin_amdgcn_s_barrier();
    asm volatile("" ::: "memory");

    const unsigned short* wbuf = &Wd[mc & 1][0];
    f32x4 acc0 = (f32x4)0.f, acc1 = (f32x4)0.f;
    #pragma unroll
    for (int ks = 0; ks < 6; ++ks) {
      const int gk = ks * 4 + lq;
      int rW = wm * 16 + lr;
      int sg = (gk & ~7) | ((gk & 7) ^ (rW & 7));
      short8 w8 = *(const short8*)&wbuf[rW * CCH + sg * 8];
      acc0 = __builtin_amdgcn_mfma_f32_16x16x32_bf16(bfr[0][ks], w8, acc0, 0, 0, 0);
      acc1 = __builtin_amdgcn_mfma_f32_16x16x32_bf16(bfr[1][ks], w8, acc1, 0, 0, 0);
    }

    {
      int m = wm * 16 + lr;  // local row 0..31, row stride 256 B (64 fp32)
      int off0 = (m * 256 + wn * 128 + lq * 16)      ^ ((m & 15) << 4);
      int off1 = (m * 256 + wn * 128 + lq * 16 + 64) ^ ((m & 15) << 4);
      *(f32x4*)(T + off0) = acc0;
      *(f32x4*)(T + off1) = acc1;
    }
    asm volatile("s_waitcnt lgkmcnt(0)" ::: "memory");
    __builtin_amdgcn_s_barrier();
    asm volatile("" ::: "memory");
    #pragma unroll
    for (int i = 0; i < 2; ++i) {
      int p = t + 256 * i;
      int row = p >> 4, seg = p & 15;
      int off = (row * 256 + seg * 16) ^ ((row & 15) << 4);
      uint4 v = *(const uint4*)(T + off);
      *(uint4*)(out + ((size_t)b * CCH + mc * 32 + row) * HWN + n0 + seg * 4) = v;
    }
    asm volatile("" ::: "memory");
    __builtin_amdgcn_s_barrier();
  }
}

// ---------------------------------------------------------------------------
extern "C" void kernel_launch(void* const* d_in, const int* in_sizes, int n_in,
                              void* d_out, int out_size, void* d_ws, size_t ws_size,
                              hipStream_t stream)
{
  const float* x       = (const float*)d_in[0];
  const float* svp_fea = (const float*)d_in[1];
  const float* qkv_w   = (const float*)d_in[2];
  const float* dw_w    = (const float*)d_in[3];
  const float* svp_w   = (const float*)d_in[4];
  const float* proj_w  = (const float*)d_in[5];
  const float* temp    = (const float*)d_in[6];
  float* outp = (float*)d_out;

  char* ws = (char*)d_ws;
  const size_t off_qkv1   = 0;
  const size_t off_qkv    = off_qkv1  + (size_t)BB*OCN*HWN*2;
  const size_t off_wb     = off_qkv   + (size_t)BB*OCN*HWN*2;
  const size_t off_svpq   = off_wb    + (size_t)OCN*CCH*2;
  const size_t off_ssqqk  = off_svpq  + (size_t)BB*12*HWN*4;
  const size_t off_ssqsvp = off_ssqqk + (size_t)BB*384*4;        // ssq_qk [b][384]
  const size_t off_Gp     = off_ssqsvp+ (size_t)BB*12*64*4;      // svp partials [b][12][64]
  const size_t off_W2     = off_Gp    + (size_t)BB*NH*16*GSZ*4;  // 5.0 MB

  unsigned short* qkv1  = (unsigned short*)(ws + off_qkv1);
  bf16*  qkv     = (bf16*)(ws + off_qkv);
  unsigned short* wb    = (unsigned short*)(ws + off_wb);
  float* svp_q   = (float*)(ws + off_svpq);
  float* ssq_qk    = (float*)(ws + off_ssqqk);
  float* ssq_svp_p = (float*)(ws + off_ssqsvp);
  float* Gp      = (float*)(ws + off_Gp);
  unsigned short* W2bf  = (unsigned short*)(ws + off_W2);

  k_castw    <<<dim3(108),         256, 0, stream>>>(qkv_w, wb);
  k_svp      <<<dim3(64, BB),      256, 0, stream>>>(svp_fea, svp_w, svp_q, ssq_svp_p);
  k_gemm     <<<dim3(128, BB),     256, 0, stream>>>(x, wb, qkv1);
  k_dw       <<<dim3(OCN, BB),     256, 0, stream>>>(qkv1, dw_w, (unsigned short*)qkv, ssq_qk);
  k_gram     <<<dim3(16, NH, BB),  256, 0, stream>>>((const unsigned short*)qkv, svp_q, Gp);
  k_attn_fold<<<dim3(NH, BB),      256, 0, stream>>>(Gp, ssq_qk, ssq_svp_p, temp, proj_w, W2bf);
  k_out      <<<dim3(256, BB),     256, 0, stream>>>((const unsigned short*)qkv, W2bf, outp);
}

// Round 17
// 260.294 us; speedup vs baseline: 1.0331x; 1.0331x over previous
//
#include <hip/hip_runtime.h>
#include <hip/hip_bf16.h>
#include <math.h>

#define BB   8
#define CCH  192
#define OCN  576
#define HWD  128
#define HWN  16384
#define NH   4
#define CHD  48
#define C51  51
#define GSZ  (C51*48)   // 2448 dense gram tile

typedef __hip_bfloat16 bf16;
typedef __attribute__((ext_vector_type(8))) short short8;
typedef __attribute__((ext_vector_type(4))) float f32x4;

__device__ __forceinline__ float bfbits2f(unsigned int u16) {
  union { unsigned int i; float f; } v; v.i = u16 << 16; return v.f;
}
__device__ __forceinline__ unsigned short f2bfbits(float f) {
  __hip_bfloat16 h = __float2bfloat16(f);
  return *(unsigned short*)&h;
}
__device__ __forceinline__ void stage16(const void* g, void* l) {
  __builtin_amdgcn_global_load_lds(
      (const __attribute__((address_space(1))) void*)g,
      (__attribute__((address_space(3))) void*)l, 16, 0, 0);
}

// --- K0: svp 1x1 conv (3->12) + ssq partials + fused qkv_w cast (b==0) ------
__global__ __launch_bounds__(256) void k_svp(
    const float* __restrict__ svp_fea, const float* __restrict__ svp_w,
    const float* __restrict__ qkv_w,
    float* __restrict__ svp_q, float* __restrict__ ssq_svp_p,
    unsigned short* __restrict__ wb)
{
  __shared__ float lsw[4][12];
  const int b = blockIdx.y;
  const int t = threadIdx.x;
  const int n = blockIdx.x * 256 + t;
  const int wave = t >> 6;
  // fused castw: batch-0 blocks cast qkv_w (576x192 = 27648 x 4 floats)
  if (b == 0) {
    for (int i = blockIdx.x * 256 + t; i < 27648; i += 64 * 256) {
      float4 v = *(const float4*)(qkv_w + (size_t)i * 4);
      union { uint2 u; unsigned short s[4]; } pk;
      pk.s[0] = f2bfbits(v.x); pk.s[1] = f2bfbits(v.y);
      pk.s[2] = f2bfbits(v.z); pk.s[3] = f2bfbits(v.w);
      *(uint2*)(wb + (size_t)i * 4) = pk.u;
    }
  }
  const float* fb = svp_fea + (size_t)b * 3 * HWN;
  const float f0 = fb[n], f1 = fb[HWN + n], f2 = fb[2 * HWN + n];
  float* ob = svp_q + (size_t)b * 12 * HWN + n;
  #pragma unroll
  for (int r = 0; r < 12; ++r) {
    float o = svp_w[r*3]*f0 + svp_w[r*3+1]*f1 + svp_w[r*3+2]*f2;
    ob[(size_t)r * HWN] = o;
    float v = o * o;
    #pragma unroll
    for (int off = 32; off >= 1; off >>= 1) v += __shfl_down(v, off, 64);
    if ((t & 63) == 0) lsw[wave][r] = v;
  }
  __syncthreads();
  if (t < 12) {
    float s = lsw[0][t] + lsw[1][t] + lsw[2][t] + lsw[3][t];
    ssq_svp_p[((size_t)b * 12 + t) * 64 + blockIdx.x] = s;
  }
}

// ---------- K1: qkv1 = W(bf16) @ x(f32->bf16), MFMA 16x16x32 ----------------
// BN=128, swapped operands, T-epilogue (256B stores), two-phase X staging.
__global__ __launch_bounds__(256) void k_gemm(
    const float* __restrict__ x, const unsigned short* __restrict__ wb,
    unsigned short* __restrict__ qkv1)
{
  __shared__ unsigned short Xs[64 * CCH];     // 24 KB; first 8 KB reused as T
  __shared__ unsigned short Wd[2][32 * CCH];  // 2 x 12 KB
  const int b = blockIdx.y;
  const int n0 = blockIdx.x * 128;
  const int t = threadIdx.x;
  const int lane = t & 63, wave = t >> 6;
  const int wm = wave >> 1, wn = wave & 1;
  const int lq = lane >> 4, lr = lane & 15;

  #pragma unroll
  for (int i = 0; i < 3; ++i) {
    int chunk = wave * 3 + i;
    int d = chunk * 64 + lane;
    int row = d / 24, kg = d % 24;
    int skg = (kg & ~7) | ((kg & 7) ^ (row & 7));
    stage16(wb + (size_t)row * CCH + skg * 8, &Wd[0][0] + chunk * 512);
  }

  const float* xb = x + (size_t)b * CCH * HWN + n0;
  short8 bfr[4][6];
  #pragma unroll 1
  for (int ph = 0; ph < 2; ++ph) {
    #pragma unroll
    for (int rr = 0; rr < 6; ++rr) {
      int idx = rr * 256 + t;
      int cp = idx >> 4, nq = idx & 15;
      int c0 = cp * 2;
      const float* xsrc = xb + (size_t)c0 * HWN + ph * 64 + nq * 4;
      float4 v0 = *(const float4*)xsrc;
      float4 v1 = *(const float4*)(xsrc + HWN);
      int g = c0 >> 3, co = c0 & 7;
      float a0[4] = {v0.x, v0.y, v0.z, v0.w};
      float a1[4] = {v1.x, v1.y, v1.z, v1.w};
      #pragma unroll
      for (int j = 0; j < 4; ++j) {
        int n = nq * 4 + j;   // local row 0..63
        int gs = (g & ~7) | ((g & 7) ^ (n & 7) ^ ((n >> 3) & 7));
        unsigned int pk = (unsigned int)f2bfbits(a0[j])
                        | ((unsigned int)f2bfbits(a1[j]) << 16);
        *(unsigned int*)&Xs[n * CCH + gs * 8 + co] = pk;
      }
    }
    __syncthreads();
    if (wn == ph) {
      #pragma unroll
      for (int nf = 0; nf < 4; ++nf) {
        int r = nf * 16 + lr;   // local row
        #pragma unroll
        for (int ks = 0; ks < 6; ++ks) {
          int gk = ks * 4 + lq;
          int sg = (gk & ~7) | ((gk & 7) ^ (r & 7) ^ ((r >> 3) & 7));
          bfr[nf][ks] = *(const short8*)&Xs[r * CCH + sg * 8];
        }
      }
    }
    __syncthreads();
  }

  unsigned short* T = &Xs[0];  // 32 x 128 bf16 transpose tile (8 KB)

  for (int mc = 0; mc < 18; ++mc) {
    if (mc + 1 < 18) {
      const unsigned short* wsrc = wb + (size_t)(mc + 1) * 32 * CCH;
      unsigned short* nb = &Wd[(mc + 1) & 1][0];
      #pragma unroll
      for (int i = 0; i < 3; ++i) {
        int chunk = wave * 3 + i;
        int d = chunk * 64 + lane;
        int row = d / 24, kg = d % 24;
        int skg = (kg & ~7) | ((kg & 7) ^ (row & 7));
        stage16(wsrc + (size_t)row * CCH + skg * 8, nb + chunk * 512);
      }
      asm volatile("s_waitcnt vmcnt(3)" ::: "memory");
    } else {
      asm volatile("s_waitcnt vmcnt(0)" ::: "memory");
    }
    __builtin_amdgcn_s_barrier();
    asm volatile("" ::: "memory");

    const unsigned short* wbuf = &Wd[mc & 1][0];
    f32x4 acc[4];
    #pragma unroll
    for (int nf = 0; nf < 4; ++nf) acc[nf] = (f32x4)0.f;

    #pragma unroll
    for (int ks = 0; ks < 6; ++ks) {
      const int gk = ks * 4 + lq;
      int rW = wm * 16 + lr;
      int sg = (gk & ~7) | ((gk & 7) ^ (rW & 7));
      short8 w8 = *(const short8*)&wbuf[rW * CCH + sg * 8];
      #pragma unroll
      for (int nf = 0; nf < 4; ++nf)
        acc[nf] = __builtin_amdgcn_mfma_f32_16x16x32_bf16(
            bfr[nf][ks], w8, acc[nf], 0, 0, 0);
    }

    {
      int m = wm * 16 + lr;  // local row 0..31
      #pragma unroll
      for (int nf = 0; nf < 4; ++nf) {
        union { unsigned long long u; unsigned short s[4]; } pk;
        #pragma unroll
        for (int r = 0; r < 4; ++r) pk.s[r] = f2bfbits(acc[nf][r]);
        int off = (m * 256 + wn * 128 + nf * 32 + lq * 8) ^ ((m & 15) << 4);
        *(unsigned long long*)((char*)T + off) = pk.u;
      }
    }
    asm volatile("s_waitcnt lgkmcnt(0)" ::: "memory");
    __builtin_amdgcn_s_barrier();
    asm volatile("" ::: "memory");
    #pragma unroll
    for (int i = 0; i < 2; ++i) {
      int p = t + 256 * i;
      int row = p >> 4, seg = p & 15;
      int off = (row * 256 + seg * 16) ^ ((row & 15) << 4);
      uint4 v = *(const uint4*)((const char*)T + off);
      *(uint4*)(qkv1 + ((size_t)b * OCN + mc * 32 + row) * HWN + n0 + seg * 8) = v;
    }
    asm volatile("" ::: "memory");
    __builtin_amdgcn_s_barrier();
  }
}

// ---------- K1b: depthwise 3x3 conv, rolling 3-row window, 8 rows/thread ----
__global__ __launch_bounds__(256) void k_dw(
    const unsigned short* __restrict__ qkv1, const float* __restrict__ dw_w,
    unsigned short* __restrict__ qkv, float* __restrict__ ssq_qk)
{
  __shared__ float lsw[4];
  const int b = blockIdx.y, c = blockIdx.x;
  const int t = threadIdx.x;
  const int cg = t & 15, rg = t >> 4;
  const int y0 = rg * 8;
  const unsigned short* src = qkv1 + ((size_t)b * OCN + c) * HWN;
  unsigned short* dst = qkv + ((size_t)b * OCN + c) * HWN;
  float w[9];
  #pragma unroll
  for (int i = 0; i < 9; ++i) w[i] = dw_w[c * 9 + i];

  auto load_row = [&](int gy, float* r) {
    uint4 B = make_uint4(0u, 0u, 0u, 0u);
    unsigned int Al = 0, Cv = 0;
    if ((unsigned)gy < 128u) {
      const unsigned short* rp = src + (size_t)gy * HWD;
      B = *(const uint4*)(rp + cg * 8);
      if (cg > 0)  Al = *(const unsigned int*)(rp + cg * 8 - 2);
      if (cg < 15) Cv = (unsigned int)rp[cg * 8 + 8];
    }
    r[0] = bfbits2f(Al >> 16);
    unsigned int ub[4] = {B.x, B.y, B.z, B.w};
    #pragma unroll
    for (int q = 0; q < 4; ++q) {
      r[1 + 2*q] = bfbits2f(ub[q] & 0xffffu);
      r[2 + 2*q] = bfbits2f(ub[q] >> 16);
    }
    r[9] = bfbits2f(Cv);
  };

  float rows[3][10];
  load_row(y0 - 1, rows[0]);
  load_row(y0,     rows[1]);
  float ssq = 0.f;
  #pragma unroll
  for (int e = 0; e < 8; ++e) {
    load_row(y0 + e + 1, rows[(e + 2) % 3]);
    const float* ra = rows[e % 3];
    const float* rb = rows[(e + 1) % 3];
    const float* rc = rows[(e + 2) % 3];
    float acc[8];
    #pragma unroll
    for (int i = 0; i < 8; ++i) acc[i] = 0.f;
    #pragma unroll
    for (int i = 0; i < 8; ++i)
      acc[i] += w[0]*ra[i] + w[1]*ra[i+1] + w[2]*ra[i+2];
    #pragma unroll
    for (int i = 0; i < 8; ++i)
      acc[i] += w[3]*rb[i] + w[4]*rb[i+1] + w[5]*rb[i+2];
    #pragma unroll
    for (int i = 0; i < 8; ++i)
      acc[i] += w[6]*rc[i] + w[7]*rc[i+1] + w[8]*rc[i+2];
    union { uint4 u; unsigned short s[8]; } pk;
    #pragma unroll
    for (int i = 0; i < 8; ++i) pk.s[i] = f2bfbits(acc[i]);
    *(uint4*)(dst + (size_t)(y0 + e) * HWD + cg * 8) = pk.u;
    if (c < 384) {
      #pragma unroll
      for (int i = 0; i < 8; ++i) {
        float rv = bfbits2f(pk.s[i]);
        ssq += rv * rv;
      }
    }
  }
  if (c < 384) {
    #pragma unroll
    for (int off = 32; off >= 1; off >>= 1) ssq += __shfl_down(ssq, off, 64);
    if ((t & 63) == 0) lsw[t >> 6] = ssq;
  }
  __syncthreads();
  if (c < 384 && t == 0)
    ssq_qk[(size_t)b * 384 + c] = lsw[0] + lsw[1] + lsw[2] + lsw[3];
}

// ---------- K3: Gram partials via MFMA, 8 chunks (2x K-work/block) ----------
__global__ __launch_bounds__(256) void k_gram(
    const unsigned short* __restrict__ qkv, const float* __restrict__ svp_q,
    float* __restrict__ Gp)
{
  __shared__ float Gs[C51 * 50];  // row stride 50: 2-way banks max
  const int chunk = blockIdx.x, h = blockIdx.y, b = blockIdx.z;
  const int t = threadIdx.x;
  const int lane = t & 63, wave = t >> 6;
  const int lq = lane >> 4, lr = lane & 15;
  const unsigned short* qb = qkv + ((size_t)b*OCN + h*CHD)*HWN;
  const unsigned short* kb = qkv + ((size_t)b*OCN + 192 + h*CHD)*HWN;
  const float* sb = svp_q + ((size_t)b*12 + h*3)*HWN;

  for (int idx = t; idx < C51*50; idx += 256) Gs[idx] = 0.f;

  f32x4 acc[3][3], sacc[3];
  #pragma unroll
  for (int mf = 0; mf < 3; ++mf)
    #pragma unroll
    for (int nf = 0; nf < 3; ++nf) acc[mf][nf] = (f32x4)0.f;
  #pragma unroll
  for (int nf = 0; nf < 3; ++nf) sacc[nf] = (f32x4)0.f;

  const int nbase = chunk * 2048 + wave * 512;
  #pragma unroll 4
  for (int ks = 0; ks < 16; ++ks) {
    const int n = nbase + ks * 32 + lq * 8;
    short8 a[3], bb[3];
    #pragma unroll
    for (int mf = 0; mf < 3; ++mf)
      a[mf] = *(const short8*)&qb[(size_t)(mf*16 + lr)*HWN + n];
    #pragma unroll
    for (int nf = 0; nf < 3; ++nf)
      bb[nf] = *(const short8*)&kb[(size_t)(nf*16 + lr)*HWN + n];
    union { short8 s8; unsigned short us[8]; } sv;
    #pragma unroll
    for (int i = 0; i < 8; ++i) sv.us[i] = 0;
    if (lr < 3) {
      const float* sp = sb + (size_t)lr*HWN + n;
      float4 v0 = *(const float4*)sp, v1 = *(const float4*)(sp + 4);
      sv.us[0] = f2bfbits(v0.x); sv.us[1] = f2bfbits(v0.y);
      sv.us[2] = f2bfbits(v0.z); sv.us[3] = f2bfbits(v0.w);
      sv.us[4] = f2bfbits(v1.x); sv.us[5] = f2bfbits(v1.y);
      sv.us[6] = f2bfbits(v1.z); sv.us[7] = f2bfbits(v1.w);
    }
    #pragma unroll
    for (int mf = 0; mf < 3; ++mf)
      #pragma unroll
      for (int nf = 0; nf < 3; ++nf)
        acc[mf][nf] = __builtin_amdgcn_mfma_f32_16x16x32_bf16(
            a[mf], bb[nf], acc[mf][nf], 0, 0, 0);
    #pragma unroll
    for (int nf = 0; nf < 3; ++nf)
      sacc[nf] = __builtin_amdgcn_mfma_f32_16x16x32_bf16(
          sv.s8, bb[nf], sacc[nf], 0, 0, 0);
  }

  __syncthreads();
  for (int w = 0; w < 4; ++w) {
    if (wave == w) {
      #pragma unroll
      for (int mf = 0; mf < 3; ++mf)
        #pragma unroll
        for (int nf = 0; nf < 3; ++nf)
          #pragma unroll
          for (int r = 0; r < 4; ++r)
            Gs[(mf*16 + lq*4 + r)*50 + nf*16 + lr] += acc[mf][nf][r];
      if (lq == 0) {
        #pragma unroll
        for (int nf = 0; nf < 3; ++nf)
          #pragma unroll
          for (int r = 0; r < 3; ++r)
            Gs[(48 + r)*50 + nf*16 + lr] += sacc[nf][r];
      }
    }
    __syncthreads();
  }
  float* Gout = Gp + ((size_t)((b*NH + h) * 8 + chunk)) * GSZ;
  for (int idx = t; idx < GSZ; idx += 256) {
    int row = idx / 48, col = idx - row * 48;
    Gout[idx] = Gs[row*50 + col];
  }
}

// ---- K4: reduce Gp(8) + ssq; softmax; fold with proj_w -> W2 (bf16) --------
__global__ __launch_bounds__(256) void k_attn_fold(
    const float* __restrict__ Gp, const float* __restrict__ ssq_qk,
    const float* __restrict__ ssq_svp_p, const float* __restrict__ temperature,
    const float* __restrict__ proj_w, unsigned short* __restrict__ W2bf)
{
  __shared__ float A[GSZ];
  __shared__ float qinv[C51];
  __shared__ float kinv[48];
  const int h = blockIdx.x, b = blockIdx.y;
  const int t = threadIdx.x;
  const float* Gb = Gp + ((size_t)(b*NH + h) * 8) * GSZ;
  if (t < 48)
    kinv[t] = 1.f / fmaxf(sqrtf(ssq_qk[(size_t)b*384 + 192 + h*48 + t]), 1e-12f);
  if (t >= 64 && t < 64 + C51) {
    int c = t - 64;
    float ss;
    if (c < 48) {
      ss = ssq_qk[(size_t)b*384 + h*48 + c];
    } else {
      const float* p = ssq_svp_p + ((size_t)b * 12 + h*3 + (c - 48)) * 64;
      float s0 = 0.f, s1 = 0.f, s2 = 0.f, s3 = 0.f;
      #pragma unroll
      for (int i = 0; i < 16; ++i) {
        float4 v = *(const float4*)(p + i * 4);
        s0 += v.x; s1 += v.y; s2 += v.z; s3 += v.w;
      }
      ss = (s0 + s1) + (s2 + s3);
    }
    qinv[c] = 1.f / fmaxf(sqrtf(ss), 1e-12f);
  }
  for (int idx = t; idx < GSZ; idx += 256) {
    float s = 0.f;
    #pragma unroll
    for (int c = 0; c < 8; ++c) s += Gb[(size_t)c * GSZ + idx];
    A[idx] = s;
  }
  __syncthreads();
  const float temp = temperature[h];
  if (t < C51) {
    float row[48];
    float m = -1e30f;
    const float qi = qinv[t] * temp;
    #pragma unroll
    for (int d = 0; d < 48; ++d) {
      float l = A[t*48 + d] * qi * kinv[d];
      row[d] = l; m = fmaxf(m, l);
    }
    float s = 0.f;
    #pragma unroll
    for (int d = 0; d < 48; ++d) { row[d] = expf(row[d] - m); s += row[d]; }
    const float inv = 1.f / s;
    #pragma unroll
    for (int d = 0; d < 48; ++d) A[t*48 + d] = row[d] * inv;
  }
  __syncthreads();
  for (int idx = t; idx < 192*48; idx += 256) {
    int o = idx / 48, d = idx - o*48;
    const float* pw = proj_w + o*204 + C51*h;
    float s = 0.f;
    #pragma unroll
    for (int c = 0; c < C51; ++c) s += pw[c] * A[c*48 + d];
    W2bf[((size_t)b*CCH + o)*CCH + h*48 + d] = f2bfbits(s);
  }
}

// ---------- K5: out[b] = W2b(bf16) @ v(bf16), T-epilogue fp32 stores --------
__global__ __launch_bounds__(256) void k_out(
    const unsigned short* __restrict__ qkv, const unsigned short* __restrict__ w2b,
    float* __restrict__ out)
{
  __shared__ unsigned short Vs[64 * CCH];     // 24 KB; first 8 KB reused as T
  __shared__ unsigned short Wd[2][32 * CCH];  // 2 x 12 KB
  const int b = blockIdx.y;
  const int n0 = blockIdx.x * 64;
  const int t = threadIdx.x;
  const int lane = t & 63, wave = t >> 6;
  const int wm = wave >> 1, wn = wave & 1;
  const int lq = lane >> 4, lr = lane & 15;

  const unsigned short* w2base = w2b + (size_t)b * CCH * CCH;
  #pragma unroll
  for (int i = 0; i < 3; ++i) {
    int chunk = wave * 3 + i;
    int d = chunk * 64 + lane;
    int row = d / 24, kg = d % 24;
    int skg = (kg & ~7) | ((kg & 7) ^ (row & 7));
    stage16(w2base + (size_t)row * CCH + skg * 8, &Wd[0][0] + chunk * 512);
  }

  const unsigned short* vb = qkv + ((size_t)b * OCN + 384) * HWN + n0;
  #pragma unroll
  for (int rr = 0; rr < 3; ++rr) {
    int idx = rr * 256 + t;
    int cp = idx >> 3, nq = idx & 7;
    int c0 = cp * 2;
    uint4 v0 = *(const uint4*)(vb + (size_t)c0 * HWN + nq * 8);
    uint4 v1 = *(const uint4*)(vb + (size_t)(c0 + 1) * HWN + nq * 8);
    union { uint4 u; unsigned short s[8]; } p0, p1;
    p0.u = v0; p1.u = v1;
    int g = c0 >> 3, co = c0 & 7;
    #pragma unroll
    for (int j = 0; j < 8; ++j) {
      int n = nq * 8 + j;
      int gs = (g & ~7) | ((g & 7) ^ (n & 7) ^ ((n >> 3) & 7));
      unsigned int pk = (unsigned int)p0.s[j] | ((unsigned int)p1.s[j] << 16);
      *(unsigned int*)&Vs[n * CCH + gs * 8 + co] = pk;
    }
  }
  __syncthreads();

  short8 bfr[2][6];
  #pragma unroll
  for (int nf = 0; nf < 2; ++nf) {
    int r = wn * 32 + nf * 16 + lr;
    #pragma unroll
    for (int ks = 0; ks < 6; ++ks) {
      int gk = ks * 4 + lq;
      int sg = (gk & ~7) | ((gk & 7) ^ (r & 7) ^ ((r >> 3) & 7));
      bfr[nf][ks] = *(const short8*)&Vs[r * CCH + sg * 8];
    }
  }
  __syncthreads();   // all waves done reading Vs before T (=Vs) is written

  char* T = (char*)&Vs[0];  // 32 m x 64 n fp32 transpose tile (8 KB)

  for (int mc = 0; mc < 6; ++mc) {
    if (mc + 1 < 6) {
      const unsigned short* wsrc = w2base + (size_t)(mc + 1) * 32 * CCH;
      unsigned short* nb = &Wd[(mc + 1) & 1][0];
      #pragma unroll
      for (int i = 0; i < 3; ++i) {
        int chunk = wave * 3 + i;
        int d = chunk * 64 + lane;
        int row = d / 24, kg = d % 24;
        int skg = (kg & ~7) | ((kg & 7) ^ (row & 7));
        stage16(wsrc + (size_t)row * CCH + skg * 8, nb + chunk * 512);
      }
      asm volatile("s_waitcnt vmcnt(3)" ::: "memory");
    } else {
      asm volatile("s_waitcnt vmcnt(0)" ::: "memory");
    }
    __builtin_amdgcn_s_barrier();
    asm volatile("" ::: "memory");

    const unsigned short* wbuf = &Wd[mc & 1][0];
    f32x4 acc0 = (f32x4)0.f, acc1 = (f32x4)0.f;
    #pragma unroll
    for (int ks = 0; ks < 6; ++ks) {
      const int gk = ks * 4 + lq;
      int rW = wm * 16 + lr;
      int sg = (gk & ~7) | ((gk & 7) ^ (rW & 7));
      short8 w8 = *(const short8*)&wbuf[rW * CCH + sg * 8];
      acc0 = __builtin_amdgcn_mfma_f32_16x16x32_bf16(bfr[0][ks], w8, acc0, 0, 0, 0);
      acc1 = __builtin_amdgcn_mfma_f32_16x16x32_bf16(bfr[1][ks], w8, acc1, 0, 0, 0);
    }

    {
      int m = wm * 16 + lr;  // local row 0..31, row stride 256 B (64 fp32)
      int off0 = (m * 256 + wn * 128 + lq * 16)      ^ ((m & 15) << 4);
      int off1 = (m * 256 + wn * 128 + lq * 16 + 64) ^ ((m & 15) << 4);
      *(f32x4*)(T + off0) = acc0;
      *(f32x4*)(T + off1) = acc1;
    }
    asm volatile("s_waitcnt lgkmcnt(0)" ::: "memory");
    __builtin_amdgcn_s_barrier();
    asm volatile("" ::: "memory");
    #pragma unroll
    for (int i = 0; i < 2; ++i) {
      int p = t + 256 * i;
      int row = p >> 4, seg = p & 15;
      int off = (row * 256 + seg * 16) ^ ((row & 15) << 4);
      uint4 v = *(const uint4*)(T + off);
      *(uint4*)(out + ((size_t)b * CCH + mc * 32 + row) * HWN + n0 + seg * 4) = v;
    }
    asm volatile("" ::: "memory");
    __builtin_amdgcn_s_barrier();
  }
}

// ---------------------------------------------------------------------------
extern "C" void kernel_launch(void* const* d_in, const int* in_sizes, int n_in,
                              void* d_out, int out_size, void* d_ws, size_t ws_size,
                              hipStream_t stream)
{
  const float* x       = (const float*)d_in[0];
  const float* svp_fea = (const float*)d_in[1];
  const float* qkv_w   = (const float*)d_in[2];
  const float* dw_w    = (const float*)d_in[3];
  const float* svp_w   = (const float*)d_in[4];
  const float* proj_w  = (const float*)d_in[5];
  const float* temp    = (const float*)d_in[6];
  float* outp = (float*)d_out;

  char* ws = (char*)d_ws;
  const size_t off_qkv1   = 0;
  const size_t off_qkv    = off_qkv1  + (size_t)BB*OCN*HWN*2;
  const size_t off_wb     = off_qkv   + (size_t)BB*OCN*HWN*2;
  const size_t off_svpq   = off_wb    + (size_t)OCN*CCH*2;
  const size_t off_ssqqk  = off_svpq  + (size_t)BB*12*HWN*4;
  const size_t off_ssqsvp = off_ssqqk + (size_t)BB*384*4;        // ssq_qk [b][384]
  const size_t off_Gp     = off_ssqsvp+ (size_t)BB*12*64*4;      // svp partials [b][12][64]
  const size_t off_W2     = off_Gp    + (size_t)BB*NH*8*GSZ*4;   // 2.5 MB

  unsigned short* qkv1  = (unsigned short*)(ws + off_qkv1);
  bf16*  qkv     = (bf16*)(ws + off_qkv);
  unsigned short* wb    = (unsigned short*)(ws + off_wb);
  float* svp_q   = (float*)(ws + off_svpq);
  float* ssq_qk    = (float*)(ws + off_ssqqk);
  float* ssq_svp_p = (float*)(ws + off_ssqsvp);
  float* Gp      = (float*)(ws + off_Gp);
  unsigned short* W2bf  = (unsigned short*)(ws + off_W2);

  k_svp      <<<dim3(64, BB),      256, 0, stream>>>(svp_fea, svp_w, qkv_w, svp_q, ssq_svp_p, wb);
  k_gemm     <<<dim3(128, BB),     256, 0, stream>>>(x, wb, qkv1);
  k_dw       <<<dim3(OCN, BB),     256, 0, stream>>>(qkv1, dw_w, (unsigned short*)qkv, ssq_qk);
  k_gram     <<<dim3(8, NH, BB),   256, 0, stream>>>((const unsigned short*)qkv, svp_q, Gp);
  k_attn_fold<<<dim3(NH, BB),      256, 0, stream>>>(Gp, ssq_qk, ssq_svp_p, temp, proj_w, W2bf);
  k_out      <<<dim3(256, BB),     256, 0, stream>>>((const unsigned short*)qkv, W2bf, outp);
}